// Round 1
// baseline (110.394 us; speedup 1.0000x reference)
//
#include <hip/hip_runtime.h>
#include <hip/hip_bf16.h>
#include <stdint.h>

#define BB 2
#define SS 2048
#define DD 512
#define PP 13
#define TT 5
#define MH 64
#define MM (BB*SS)      // 4096 rows
#define NV (TT*DD)      // 2560
#define KK 512
#define CHUNK 16
#define NCH (SS/CHUNK)  // 128

typedef __attribute__((ext_vector_type(4))) float f32x4;
typedef __attribute__((ext_vector_type(8))) short s8v;

__device__ __forceinline__ float bf2f(unsigned short u){
  union { unsigned int i; float f; } c; c.i = ((unsigned int)u) << 16; return c.f;
}
__device__ __forceinline__ unsigned short f2bf(float f){
  union { float f; unsigned int i; } c; c.f = f;
  unsigned int x = c.i;
  unsigned int r = (x + 0x7fffu + ((x >> 16) & 1u)) >> 16;
  return (unsigned short)r;
}

// ---------------------------------------------------------------- W_v = mix-contracted W_in (stored transposed, bf16), b_v
__global__ __launch_bounds__(256) void k_prep_wv(
    const float* __restrict__ W_in, const float* __restrict__ b_in,
    const float* __restrict__ mix,
    unsigned short* __restrict__ W_vT, float* __restrict__ b_v)
{
  int idx = blockIdx.x * 256 + threadIdx.x;   // 32768 total
  int d  = idx & (DD-1);
  int k0 = idx >> 9;                          // 0..63 (8 k's each)
  float mx[PP][TT];
  #pragma unroll
  for (int p=0;p<PP;++p)
    #pragma unroll
    for (int t=0;t<TT;++t) mx[p][t] = mix[p*TT+t];
  float acc[TT][8];
  #pragma unroll
  for (int t=0;t<TT;++t)
    #pragma unroll
    for (int j=0;j<8;++j) acc[t][j] = 0.f;
  #pragma unroll
  for (int j=0;j<8;++j){
    int k = k0*8 + j;
    const float* wrow = W_in + (size_t)k * (PP*DD) + d;
    #pragma unroll
    for (int p=0;p<PP;++p){
      float w = wrow[p*DD];
      #pragma unroll
      for (int t=0;t<TT;++t) acc[t][j] += mx[p][t]*w;
    }
  }
  #pragma unroll
  for (int t=0;t<TT;++t){
    union { unsigned short us[8]; uint4 u; } pk;
    #pragma unroll
    for (int j=0;j<8;++j) pk.us[j] = f2bf(acc[t][j]);
    *(uint4*)(W_vT + ((size_t)(t*DD+d))*KK + k0*8) = pk.u;
  }
  if (k0 == 0){
    #pragma unroll
    for (int t=0;t<TT;++t){
      float s = 0.f;
      #pragma unroll
      for (int p=0;p<PP;++p) s += mx[p][t]*b_in[p*DD+d];
      b_v[t*DD+d] = s;
    }
  }
}

// ---------------------------------------------------------------- W_out^T bf16
__global__ __launch_bounds__(256) void k_prep_wout(
    const float* __restrict__ W_out, unsigned short* __restrict__ W_outT)
{
  int idx = blockIdx.x*256 + threadIdx.x; // 32768
  int n  = idx & (DD-1);
  int k0 = idx >> 9;
  union { unsigned short us[8]; uint4 u; } pk;
  #pragma unroll
  for (int j=0;j<8;++j) pk.us[j] = f2bf(W_out[(size_t)(k0*8+j)*DD + n]);
  *(uint4*)(W_outT + (size_t)n*KK + k0*8) = pk.u;
}

// ---------------------------------------------------------------- LayerNorm + gate/alpha (one block per row)
__global__ __launch_bounds__(256) void k_ln_gate(
    const float* __restrict__ hs,
    const float* __restrict__ gamma, const float* __restrict__ beta,
    const float* __restrict__ W1, const float* __restrict__ b1,
    const float* __restrict__ W2, const float* __restrict__ b2,
    const float* __restrict__ log_tau,
    unsigned short* __restrict__ xn_bf, float* __restrict__ alpha)
{
  int row = blockIdx.x;
  int tid = threadIdx.x;
  __shared__ float sxn[DD];
  __shared__ float red[8];
  __shared__ float zp[4][MH];
  __shared__ float z1[MH];
  const float* x = hs + (size_t)row*DD;
  float2 v = *(const float2*)(x + tid*2);
  float s  = v.x + v.y;
  float sq = v.x*v.x + v.y*v.y;
  #pragma unroll
  for (int o=32;o>0;o>>=1){ s += __shfl_xor(s,o); sq += __shfl_xor(sq,o); }
  if ((tid & 63) == 0){ red[tid>>6] = s; red[4+(tid>>6)] = sq; }
  __syncthreads();
  float tot  = red[0]+red[1]+red[2]+red[3];
  float tot2 = red[4]+red[5]+red[6]+red[7];
  float mu   = tot  * (1.f/DD);
  float var  = tot2 * (1.f/DD) - mu*mu;
  float rstd = rsqrtf(var + 1e-5f);
  float xn0 = (v.x - mu)*rstd*gamma[tid*2]   + beta[tid*2];
  float xn1 = (v.y - mu)*rstd*gamma[tid*2+1] + beta[tid*2+1];
  sxn[tid*2] = xn0; sxn[tid*2+1] = xn1;
  ushort2 ob; ob.x = f2bf(xn0); ob.y = f2bf(xn1);
  *(ushort2*)(xn_bf + (size_t)row*DD + tid*2) = ob;
  __syncthreads();
  int h = tid & 63, q = tid >> 6;
  float part = 0.f;
  for (int k = q*128; k < q*128+128; ++k) part += sxn[k]*W1[(size_t)k*MH + h];
  zp[q][h] = part;
  __syncthreads();
  if (tid < MH){
    float z = zp[0][tid]+zp[1][tid]+zp[2][tid]+zp[3][tid] + b1[tid];
    z1[tid] = tanhf(z);
  }
  __syncthreads();
  if (tid < TT){
    float z2 = b2[tid];
    #pragma unroll
    for (int hh=0; hh<MH; ++hh) z2 += z1[hh]*W2[hh*TT + tid];
    float gate = 1.f/(1.f + expf(-z2));
    float a = expf(-gate * expf(-log_tau[tid]));
    alpha[(size_t)row*TT + tid] = a;
  }
}

// ---------------------------------------------------------------- bf16 MFMA GEMM: C = A(M,K) * Bt(N,K)^T (+bias) [+epilogue]
template<int NDIM, bool OUTEPI>
__global__ __launch_bounds__(256) void k_gemm(
    const unsigned short* __restrict__ A,
    const unsigned short* __restrict__ Bt,
    const float* __restrict__ bias,
    const float* __restrict__ hidden,
    const float* __restrict__ scale_p,
    float* __restrict__ outF,
    unsigned short* __restrict__ outBf)
{
  __shared__ unsigned short lA[128*40];  // pad 32->40 elems: b128 reads land 2-way max (free)
  __shared__ unsigned short lB[128*40];
  int bn = blockIdx.x, bm = blockIdx.y;
  int tid = threadIdx.x;
  int l = tid & 63;
  int wid = tid >> 6;
  int wm = wid >> 1, wn = wid & 1;
  f32x4 acc[4][4];
  #pragma unroll
  for (int i=0;i<4;++i)
    #pragma unroll
    for (int j=0;j<4;++j) acc[i][j] = (f32x4){0.f,0.f,0.f,0.f};
  int srow = tid >> 2, skq = tid & 3;
  const unsigned short* Ab = A  + (size_t)(bm*128 + srow)*KK + skq*8;
  const unsigned short* Bb = Bt + (size_t)(bn*128 + srow)*KK + skq*8;
  int lr = l & 15, kq = l >> 4;
  for (int ks = 0; ks < KK; ks += 32){
    uint4 a0 = *(const uint4*)(Ab + ks);
    uint4 a1 = *(const uint4*)(Ab + (size_t)64*KK + ks);
    uint4 b0 = *(const uint4*)(Bb + ks);
    uint4 b1 = *(const uint4*)(Bb + (size_t)64*KK + ks);
    __syncthreads();
    *(uint4*)&lA[srow*40 + skq*8]      = a0;
    *(uint4*)&lA[(srow+64)*40 + skq*8] = a1;
    *(uint4*)&lB[srow*40 + skq*8]      = b0;
    *(uint4*)&lB[(srow+64)*40 + skq*8] = b1;
    __syncthreads();
    union { uint4 u; s8v v; } af[4], bfr[4];
    #pragma unroll
    for (int mi=0;mi<4;++mi) af[mi].u  = *(const uint4*)&lA[(wm*64+mi*16+lr)*40 + kq*8];
    #pragma unroll
    for (int ni=0;ni<4;++ni) bfr[ni].u = *(const uint4*)&lB[(wn*64+ni*16+lr)*40 + kq*8];
    #pragma unroll
    for (int mi=0;mi<4;++mi)
      #pragma unroll
      for (int ni=0;ni<4;++ni)
        acc[mi][ni] = __builtin_amdgcn_mfma_f32_16x16x32_bf16(af[mi].v, bfr[ni].v, acc[mi][ni], 0,0,0);
  }
  float sc = 0.f;
  if constexpr (OUTEPI) sc = *scale_p;
  #pragma unroll
  for (int mi=0;mi<4;++mi){
    #pragma unroll
    for (int ni=0;ni<4;++ni){
      int row = bm*128 + wm*64 + mi*16 + kq*4;   // C/D: col=lane&15, row=(lane>>4)*4+reg
      int col = bn*128 + wn*64 + ni*16 + lr;
      float bs = bias[col];
      f32x4 c = acc[mi][ni];
      #pragma unroll
      for (int r=0;r<4;++r){
        float val = c[r] + bs;
        size_t off = (size_t)(row+r)*NDIM + col;
        if constexpr (OUTEPI) outF[off] = hidden[off] + sc*val;
        else                  outBf[off] = f2bf(val);
      }
    }
  }
}

// ---------------------------------------------------------------- scan phase A: chunk-local zero-init scans (g_loc over v, in place) + prefix products
__global__ __launch_bounds__(256) void k_scan_a(
    const float* __restrict__ alpha,
    unsigned short* __restrict__ vg,   // in: v (bf16), out: g_loc (bf16) in place
    float* __restrict__ prefa)
{
  int blk = blockIdx.x;           // (b*TT+t)*NCH + c
  int c  = blk % NCH;
  int bt = blk / NCH;
  int t  = bt % TT;
  int b  = bt / TT;
  int tid = threadIdx.x;          // 256, each handles d=2*tid, 2*tid+1
  float g0 = 0.f, g1 = 0.f, pa = 1.f;
  #pragma unroll
  for (int s2=0;s2<CHUNK;++s2){
    int sg = c*CHUNK + s2;
    size_t rb = (size_t)(b*SS + sg);
    float a  = alpha[rb*TT + t];
    float om = 1.f - a;
    unsigned short* vp = vg + rb*NV + t*DD + tid*2;
    ushort2 vv = *(ushort2*)vp;
    g0 = a*g0 + om*bf2f(vv.x);
    g1 = a*g1 + om*bf2f(vv.y);
    ushort2 go; go.x = f2bf(g0); go.y = f2bf(g1);
    *(ushort2*)vp = go;
    pa *= a;
    if (tid == 0) prefa[rb*TT + t] = pa;
  }
}

// ---------------------------------------------------------------- scan phase B: sequential carry over chunks (one block per (b,t))
__global__ __launch_bounds__(512) void k_scan_b(
    const float* __restrict__ mix,
    const float* __restrict__ h_prev,
    const float* __restrict__ prefa,
    const unsigned short* __restrict__ g_loc,
    float* __restrict__ Gc)
{
  int blk = blockIdx.x;      // b*TT + t  (10 blocks)
  int t = blk % TT, b = blk / TT;
  int d = threadIdx.x;       // 512
  __shared__ float sP[NCH];
  if (d < NCH) sP[d] = prefa[((size_t)(b*SS + d*CHUNK + CHUNK-1))*TT + t];
  __syncthreads();
  float carry = 0.f;         // g_init = sum_p mix[p,t]*h_prev[b,p,t,d]
  #pragma unroll
  for (int p=0;p<PP;++p)
    carry += mix[p*TT+t] * h_prev[((size_t)(b*PP+p)*TT + t)*DD + d];
  const unsigned short* gl = g_loc + (size_t)b*SS*NV + t*DD + d;
  float* gc = Gc + ((size_t)(b*TT+t))*NCH*DD + d;
  auto ldL = [&](float* L, int c0){
    #pragma unroll
    for (int j=0;j<4;++j){
      int sg = (c0+j)*CHUNK + CHUNK-1;
      L[j] = bf2f(gl[(size_t)sg*NV]);
    }
  };
  float La[4], Lb[4];
  ldL(La, 0);
  for (int c0=0;c0<NCH;c0+=8){
    ldL(Lb, c0+4);
    #pragma unroll
    for (int j=0;j<4;++j){
      gc[(size_t)(c0+j)*DD] = carry;
      carry = sP[c0+j]*carry + La[j];
    }
    if (c0+8 < NCH) ldL(La, c0+8);
    #pragma unroll
    for (int j=0;j<4;++j){
      gc[(size_t)(c0+4+j)*DD] = carry;
      carry = sP[c0+4+j]*carry + Lb[j];
    }
  }
}

// ---------------------------------------------------------------- scan phase C fused with y = sum_t g  (bf16 out for GEMM A)
__global__ __launch_bounds__(256) void k_scan_c(
    const float* __restrict__ prefa,
    const unsigned short* __restrict__ g_loc,
    const float* __restrict__ Gc,
    unsigned short* __restrict__ ybf)
{
  int row = blockIdx.x;        // b*SS+s
  int tid = threadIdx.x;       // 256 -> d = 2*tid
  int b = row >> 11;
  int s = row & (SS-1);
  int c = s / CHUNK;
  float y0=0.f, y1=0.f;
  #pragma unroll
  for (int t=0;t<TT;++t){
    float pa = prefa[(size_t)row*TT + t];
    ushort2 gl = *(const ushort2*)(g_loc + (size_t)row*NV + t*DD + tid*2);
    const float* gp = Gc + (((size_t)(b*TT+t))*NCH + c)*DD + tid*2;
    y0 += bf2f(gl.x) + pa*gp[0];
    y1 += bf2f(gl.y) + pa*gp[1];
  }
  ushort2 o; o.x=f2bf(y0); o.y=f2bf(y1);
  *(ushort2*)(ybf + (size_t)row*DD + tid*2) = o;
}

// ----------------------------------------------------------------
extern "C" void kernel_launch(void* const* d_in, const int* in_sizes, int n_in,
                              void* d_out, int out_size, void* d_ws, size_t ws_size,
                              hipStream_t stream)
{
  (void)in_sizes; (void)n_in; (void)out_size; (void)ws_size;
  const float* hs     = (const float*)d_in[0];
  const float* gamma  = (const float*)d_in[1];
  const float* beta   = (const float*)d_in[2];
  const float* W_in   = (const float*)d_in[3];
  const float* b_in   = (const float*)d_in[4];
  const float* W1     = (const float*)d_in[5];
  const float* b1     = (const float*)d_in[6];
  const float* W2     = (const float*)d_in[7];
  const float* b2     = (const float*)d_in[8];
  const float* ltau   = (const float*)d_in[9];
  const float* mix    = (const float*)d_in[10];
  const float* W_out  = (const float*)d_in[11];
  const float* b_out  = (const float*)d_in[12];
  const float* scale  = (const float*)d_in[13];
  const float* h_prev = (const float*)d_in[14];
  float* out = (float*)d_out;

  uint8_t* w = (uint8_t*)d_ws;
  unsigned short* xn   = (unsigned short*)(w);                  // 4,194,304 B
  unsigned short* WvT  = (unsigned short*)(w + 4194304);        // 2,621,440 B
  unsigned short* WoT  = (unsigned short*)(w + 6815744);        //   524,288 B
  float* alpha         = (float*)(w + 7340032);                 //    81,920 B
  float* prefa         = (float*)(w + 7421952);                 //    81,920 B
  float* b_v           = (float*)(w + 7503872);                 //    10,240 B
  unsigned short* vg   = (unsigned short*)(w + 7514112);        // 20,971,520 B (v, then g_loc in place)
  float* Gc            = (float*)(w + 28485632);                // 2,621,440 B
  unsigned short* ybf  = (unsigned short*)(w + 31107072);       // 4,194,304 B  (end ~35.3 MB)

  hipLaunchKernelGGL(k_prep_wv,  dim3(128), dim3(256), 0, stream, W_in, b_in, mix, WvT, b_v);
  hipLaunchKernelGGL(k_prep_wout,dim3(128), dim3(256), 0, stream, W_out, WoT);
  hipLaunchKernelGGL(k_ln_gate,  dim3(MM),  dim3(256), 0, stream, hs, gamma, beta, W1, b1, W2, b2, ltau, xn, alpha);
  hipLaunchKernelGGL((k_gemm<NV,false>), dim3(NV/128, MM/128), dim3(256), 0, stream,
                     xn, WvT, b_v, nullptr, nullptr, nullptr, vg);
  hipLaunchKernelGGL(k_scan_a,   dim3(BB*TT*NCH), dim3(256), 0, stream, alpha, vg, prefa);
  hipLaunchKernelGGL(k_scan_b,   dim3(BB*TT), dim3(512), 0, stream, mix, h_prev, prefa, vg, Gc);
  hipLaunchKernelGGL(k_scan_c,   dim3(MM),  dim3(256), 0, stream, prefa, vg, Gc, ybf);
  hipLaunchKernelGGL((k_gemm<DD,true>), dim3(DD/128, MM/128), dim3(256), 0, stream,
                     ybf, WoT, b_out, hs, scale, out, nullptr);
}

// Round 2
// 94.321 us; speedup vs baseline: 1.1704x; 1.1704x over previous
//
#include <hip/hip_runtime.h>
#include <hip/hip_bf16.h>
#include <stdint.h>

#define BB 2
#define SS 2048
#define DD 512
#define PP 13
#define TT 5
#define MH 64
#define MM (BB*SS)      // 4096 rows
#define NV (TT*DD)      // 2560
#define KK 512
#define CHUNK 16
#define NCH (SS/CHUNK)  // 128

typedef __attribute__((ext_vector_type(4))) float f32x4;
typedef __attribute__((ext_vector_type(8))) short s8v;
typedef unsigned int u32;
typedef __attribute__((address_space(3))) u32 lds_u32_t;
typedef __attribute__((address_space(1))) const u32 glb_u32_t;

__device__ __forceinline__ float bf2f(unsigned short u){
  union { unsigned int i; float f; } c; c.i = ((unsigned int)u) << 16; return c.f;
}
__device__ __forceinline__ unsigned short f2bf(float f){
  union { float f; unsigned int i; } c; c.f = f;
  unsigned int x = c.i;
  unsigned int r = (x + 0x7fffu + ((x >> 16) & 1u)) >> 16;
  return (unsigned short)r;
}
// async global->LDS, 16B per lane; LDS dest is wave-uniform base + lane*16
__device__ __forceinline__ void gld16(unsigned short* l, const unsigned short* g){
  __builtin_amdgcn_global_load_lds((glb_u32_t*)g, (lds_u32_t*)l, 16, 0, 0);
}

// ---------------------------------------------------------------- W_v = mix-contracted W_in (stored transposed, bf16), b_v
__global__ __launch_bounds__(256) void k_prep_wv(
    const float* __restrict__ W_in, const float* __restrict__ b_in,
    const float* __restrict__ mix,
    unsigned short* __restrict__ W_vT, float* __restrict__ b_v)
{
  int idx = blockIdx.x * 256 + threadIdx.x;   // 32768 total
  int d  = idx & (DD-1);
  int k0 = idx >> 9;                          // 0..63 (8 k's each)
  float mx[PP][TT];
  #pragma unroll
  for (int p=0;p<PP;++p)
    #pragma unroll
    for (int t=0;t<TT;++t) mx[p][t] = mix[p*TT+t];
  float acc[TT][8];
  #pragma unroll
  for (int t=0;t<TT;++t)
    #pragma unroll
    for (int j=0;j<8;++j) acc[t][j] = 0.f;
  #pragma unroll
  for (int j=0;j<8;++j){
    int k = k0*8 + j;
    const float* wrow = W_in + (size_t)k * (PP*DD) + d;
    #pragma unroll
    for (int p=0;p<PP;++p){
      float w = wrow[p*DD];
      #pragma unroll
      for (int t=0;t<TT;++t) acc[t][j] += mx[p][t]*w;
    }
  }
  #pragma unroll
  for (int t=0;t<TT;++t){
    union { unsigned short us[8]; uint4 u; } pk;
    #pragma unroll
    for (int j=0;j<8;++j) pk.us[j] = f2bf(acc[t][j]);
    *(uint4*)(W_vT + ((size_t)(t*DD+d))*KK + k0*8) = pk.u;
  }
  if (k0 == 0){
    #pragma unroll
    for (int t=0;t<TT;++t){
      float s = 0.f;
      #pragma unroll
      for (int p=0;p<PP;++p) s += mx[p][t]*b_in[p*DD+d];
      b_v[t*DD+d] = s;
    }
  }
}

// ---------------------------------------------------------------- W_out^T bf16
__global__ __launch_bounds__(256) void k_prep_wout(
    const float* __restrict__ W_out, unsigned short* __restrict__ W_outT)
{
  int idx = blockIdx.x*256 + threadIdx.x; // 32768
  int n  = idx & (DD-1);
  int k0 = idx >> 9;
  union { unsigned short us[8]; uint4 u; } pk;
  #pragma unroll
  for (int j=0;j<8;++j) pk.us[j] = f2bf(W_out[(size_t)(k0*8+j)*DD + n]);
  *(uint4*)(W_outT + (size_t)n*KK + k0*8) = pk.u;
}

// ---------------------------------------------------------------- LayerNorm + gate/alpha (one block per row)
__global__ __launch_bounds__(256) void k_ln_gate(
    const float* __restrict__ hs,
    const float* __restrict__ gamma, const float* __restrict__ beta,
    const float* __restrict__ W1, const float* __restrict__ b1,
    const float* __restrict__ W2, const float* __restrict__ b2,
    const float* __restrict__ log_tau,
    unsigned short* __restrict__ xn_bf, float* __restrict__ alpha)
{
  int row = blockIdx.x;
  int tid = threadIdx.x;
  __shared__ float sxn[DD];
  __shared__ float red[8];
  __shared__ float zp[4][MH];
  __shared__ float z1[MH];
  const float* x = hs + (size_t)row*DD;
  float2 v = *(const float2*)(x + tid*2);
  float s  = v.x + v.y;
  float sq = v.x*v.x + v.y*v.y;
  #pragma unroll
  for (int o=32;o>0;o>>=1){ s += __shfl_xor(s,o); sq += __shfl_xor(sq,o); }
  if ((tid & 63) == 0){ red[tid>>6] = s; red[4+(tid>>6)] = sq; }
  __syncthreads();
  float tot  = red[0]+red[1]+red[2]+red[3];
  float tot2 = red[4]+red[5]+red[6]+red[7];
  float mu   = tot  * (1.f/DD);
  float var  = tot2 * (1.f/DD) - mu*mu;
  float rstd = rsqrtf(var + 1e-5f);
  float xn0 = (v.x - mu)*rstd*gamma[tid*2]   + beta[tid*2];
  float xn1 = (v.y - mu)*rstd*gamma[tid*2+1] + beta[tid*2+1];
  sxn[tid*2] = xn0; sxn[tid*2+1] = xn1;
  ushort2 ob; ob.x = f2bf(xn0); ob.y = f2bf(xn1);
  *(ushort2*)(xn_bf + (size_t)row*DD + tid*2) = ob;
  __syncthreads();
  int h = tid & 63, q = tid >> 6;
  float part = 0.f;
  for (int k = q*128; k < q*128+128; ++k) part += sxn[k]*W1[(size_t)k*MH + h];
  zp[q][h] = part;
  __syncthreads();
  if (tid < MH){
    float z = zp[0][tid]+zp[1][tid]+zp[2][tid]+zp[3][tid] + b1[tid];
    z1[tid] = tanhf(z);
  }
  __syncthreads();
  if (tid < TT){
    float z2 = b2[tid];
    #pragma unroll
    for (int hh=0; hh<MH; ++hh) z2 += z1[hh]*W2[hh*TT + tid];
    float gate = 1.f/(1.f + expf(-z2));
    float a = expf(-gate * expf(-log_tau[tid]));
    alpha[(size_t)row*TT + tid] = a;
  }
}

// ---------------------------------------------------------------- m97-style bf16 MFMA GEMM: C = A(M,K) * Bt(N,K)^T (+bias) [+epilogue]
// 128xBN tile, BK=32, global_load_lds width 16, linear LDS, 2 barriers/K-step.
template<int BN, int NDIM, bool OUTEPI>
__global__ __launch_bounds__(256) void k_gemm(
    const unsigned short* __restrict__ A,
    const unsigned short* __restrict__ Bt,
    const float* __restrict__ bias,
    const float* __restrict__ hidden,
    const float* __restrict__ scale_p,
    float* __restrict__ outF,
    unsigned short* __restrict__ outBf)
{
  constexpr int NI  = (BN == 128) ? 4 : 2;   // 16-col fragments per wave
  constexpr int WNT = BN / 2;                // wave col-tile
  __shared__ unsigned short lA[128*32];
  __shared__ unsigned short lB[BN*32];
  int bn = blockIdx.x, bm = blockIdx.y;
  int tid  = threadIdx.x;
  int lane = tid & 63;
  int w    = tid >> 6;
  int wm = w >> 1, wn = w & 1;
  f32x4 acc[4][NI];
  #pragma unroll
  for (int i=0;i<4;++i)
    #pragma unroll
    for (int j=0;j<NI;++j) acc[i][j] = (f32x4){0.f,0.f,0.f,0.f};

  int r4 = lane >> 2;            // 0..15 row within staging stripe
  int cb = (lane & 3) * 16;      // byte offset within 64B row
  const uint8_t* gA = (const uint8_t*)(A + (size_t)(bm*128 + w*32 + r4)*KK) + cb;
  unsigned short* sA0 = &lA[(w*32)*32];
  unsigned short* sA1 = &lA[(w*32+16)*32];
  const uint8_t* gB;
  unsigned short* sB0; unsigned short* sB1 = nullptr;
  if constexpr (BN == 128){
    gB  = (const uint8_t*)(Bt + (size_t)(bn*BN + w*32 + r4)*KK) + cb;
    sB0 = &lB[(w*32)*32];
    sB1 = &lB[(w*32+16)*32];
  } else {
    gB  = (const uint8_t*)(Bt + (size_t)(bn*BN + w*16 + r4)*KK) + cb;
    sB0 = &lB[(w*16)*32];
  }
  int lr = lane & 15, kq = lane >> 4;

  for (int ks = 0; ks < KK; ks += 32){
    int off = ks*2;
    gld16(sA0, (const unsigned short*)(gA + off));
    gld16(sA1, (const unsigned short*)(gA + (size_t)16*KK*2 + off));
    gld16(sB0, (const unsigned short*)(gB + off));
    if constexpr (BN == 128)
      gld16(sB1, (const unsigned short*)(gB + (size_t)16*KK*2 + off));
    __syncthreads();   // drains vmcnt(0): LDS tile ready
    union { uint4 u; s8v v; } af[4], bfr[NI];
    #pragma unroll
    for (int mi=0;mi<4;++mi) af[mi].u  = *(const uint4*)&lA[(wm*64+mi*16+lr)*32 + kq*8];
    #pragma unroll
    for (int ni=0;ni<NI;++ni) bfr[ni].u = *(const uint4*)&lB[(wn*WNT+ni*16+lr)*32 + kq*8];
    #pragma unroll
    for (int mi=0;mi<4;++mi)
      #pragma unroll
      for (int ni=0;ni<NI;++ni)
        acc[mi][ni] = __builtin_amdgcn_mfma_f32_16x16x32_bf16(af[mi].v, bfr[ni].v, acc[mi][ni], 0,0,0);
    __syncthreads();   // protect LDS from next-iter overwrite
  }
  float sc = 0.f;
  if constexpr (OUTEPI) sc = *scale_p;
  #pragma unroll
  for (int mi=0;mi<4;++mi){
    #pragma unroll
    for (int ni=0;ni<NI;++ni){
      int row = bm*128 + wm*64 + mi*16 + kq*4;   // C/D: col=lane&15, row=(lane>>4)*4+reg
      int col = bn*BN  + wn*WNT + ni*16 + lr;
      float bs = bias[col];
      f32x4 c = acc[mi][ni];
      #pragma unroll
      for (int r=0;r<4;++r){
        float val = c[r] + bs;
        size_t off = (size_t)(row+r)*NDIM + col;
        if constexpr (OUTEPI) outF[off] = hidden[off] + sc*val;
        else                  outBf[off] = f2bf(val);
      }
    }
  }
}

// ---------------------------------------------------------------- scan phase A: per (b,chunk), all t: chunk-local zero-init scan
// outputs: L (chunk-end local value, dense f32) and PA (per-chunk alpha product)
__global__ __launch_bounds__(256) void k_scan_a(
    const float* __restrict__ alpha,
    const unsigned short* __restrict__ vg,
    float* __restrict__ L, float* __restrict__ PA)
{
  int blk = blockIdx.x;           // b*NCH + c
  int c = blk % NCH, b = blk / NCH;
  int tid = threadIdx.x;          // d0 = 2*tid
  __shared__ float sAl[CHUNK*TT];
  if (tid < CHUNK*TT) sAl[tid] = alpha[(size_t)(b*SS + c*CHUNK)*TT + tid];
  __syncthreads();
  float g[TT][2];
  #pragma unroll
  for (int t=0;t<TT;++t){ g[t][0]=0.f; g[t][1]=0.f; }
  const unsigned short* vp = vg + (size_t)(b*SS + c*CHUNK)*NV + tid*2;
  #pragma unroll
  for (int s2=0;s2<CHUNK;++s2){
    #pragma unroll
    for (int t=0;t<TT;++t){
      float a = sAl[s2*TT+t], om = 1.f - a;
      ushort2 vv = *(const ushort2*)(vp + (size_t)s2*NV + t*DD);
      g[t][0] = a*g[t][0] + om*bf2f(vv.x);
      g[t][1] = a*g[t][1] + om*bf2f(vv.y);
    }
  }
  #pragma unroll
  for (int t=0;t<TT;++t){
    float2 o; o.x = g[t][0]; o.y = g[t][1];
    *(float2*)(L + ((size_t)(b*TT+t)*NCH + c)*DD + tid*2) = o;
  }
  if (tid < TT){
    float pa = 1.f;
    #pragma unroll
    for (int s2=0;s2<CHUNK;++s2) pa *= sAl[s2*TT+tid];
    PA[(size_t)(b*TT+tid)*NCH + c] = pa;
  }
}

// ---------------------------------------------------------------- scan phase B: sequential carry over chunks (one block per (b,t))
// Gc[c] = true g at the START of chunk c (the carry phase C scans from)
__global__ __launch_bounds__(512) void k_scan_b(
    const float* __restrict__ mix,
    const float* __restrict__ h_prev,
    const float* __restrict__ PA,
    const float* __restrict__ L,
    float* __restrict__ Gc)
{
  int blk = blockIdx.x;      // b*TT + t  (10 blocks)
  int t = blk % TT, b = blk / TT;
  int d = threadIdx.x;       // 512
  __shared__ float sP[NCH];
  if (d < NCH) sP[d] = PA[(size_t)(b*TT+t)*NCH + d];
  __syncthreads();
  float carry = 0.f;         // g_init = sum_p mix[p,t]*h_prev[b,p,t,d]
  #pragma unroll
  for (int p=0;p<PP;++p)
    carry += mix[p*TT+t] * h_prev[((size_t)(b*PP+p)*TT + t)*DD + d];
  const float* Lp = L  + (size_t)(b*TT+t)*NCH*DD + d;
  float*       gc = Gc + (size_t)(b*TT+t)*NCH*DD + d;
  float buf[8], nbuf[8];
  #pragma unroll
  for (int j=0;j<8;++j) buf[j] = Lp[(size_t)j*DD];
  for (int c0=0;c0<NCH;c0+=8){
    if (c0+8 < NCH){
      #pragma unroll
      for (int j=0;j<8;++j) nbuf[j] = Lp[(size_t)(c0+8+j)*DD];
    }
    #pragma unroll
    for (int j=0;j<8;++j){
      gc[(size_t)(c0+j)*DD] = carry;
      carry = sP[c0+j]*carry + buf[j];
    }
    #pragma unroll
    for (int j=0;j<8;++j) buf[j] = nbuf[j];
  }
}

// ---------------------------------------------------------------- scan phase C: per (b,chunk), rescan with true carry, y = sum_t g
__global__ __launch_bounds__(256) void k_scan_c(
    const float* __restrict__ alpha,
    const unsigned short* __restrict__ vg,
    const float* __restrict__ Gc,
    unsigned short* __restrict__ ybf)
{
  int blk = blockIdx.x;           // b*NCH + c
  int c = blk % NCH, b = blk / NCH;
  int tid = threadIdx.x;
  __shared__ float sAl[CHUNK*TT];
  if (tid < CHUNK*TT) sAl[tid] = alpha[(size_t)(b*SS + c*CHUNK)*TT + tid];
  __syncthreads();
  float g[TT][2];
  #pragma unroll
  for (int t=0;t<TT;++t){
    float2 cv = *(const float2*)(Gc + ((size_t)(b*TT+t)*NCH + c)*DD + tid*2);
    g[t][0] = cv.x; g[t][1] = cv.y;
  }
  const unsigned short* vp = vg + (size_t)(b*SS + c*CHUNK)*NV + tid*2;
  unsigned short* yp = ybf + (size_t)(b*SS + c*CHUNK)*DD + tid*2;
  #pragma unroll
  for (int s2=0;s2<CHUNK;++s2){
    float y0 = 0.f, y1 = 0.f;
    #pragma unroll
    for (int t=0;t<TT;++t){
      float a = sAl[s2*TT+t], om = 1.f - a;
      ushort2 vv = *(const ushort2*)(vp + (size_t)s2*NV + t*DD);
      g[t][0] = a*g[t][0] + om*bf2f(vv.x);
      g[t][1] = a*g[t][1] + om*bf2f(vv.y);
      y0 += g[t][0]; y1 += g[t][1];
    }
    ushort2 o; o.x = f2bf(y0); o.y = f2bf(y1);
    *(ushort2*)(yp + (size_t)s2*DD) = o;
  }
}

// ----------------------------------------------------------------
extern "C" void kernel_launch(void* const* d_in, const int* in_sizes, int n_in,
                              void* d_out, int out_size, void* d_ws, size_t ws_size,
                              hipStream_t stream)
{
  (void)in_sizes; (void)n_in; (void)out_size; (void)ws_size;
  const float* hs     = (const float*)d_in[0];
  const float* gamma  = (const float*)d_in[1];
  const float* beta   = (const float*)d_in[2];
  const float* W_in   = (const float*)d_in[3];
  const float* b_in   = (const float*)d_in[4];
  const float* W1     = (const float*)d_in[5];
  const float* b1     = (const float*)d_in[6];
  const float* W2     = (const float*)d_in[7];
  const float* b2     = (const float*)d_in[8];
  const float* ltau   = (const float*)d_in[9];
  const float* mix    = (const float*)d_in[10];
  const float* W_out  = (const float*)d_in[11];
  const float* b_out  = (const float*)d_in[12];
  const float* scale  = (const float*)d_in[13];
  const float* h_prev = (const float*)d_in[14];
  float* out = (float*)d_out;

  uint8_t* w = (uint8_t*)d_ws;
  unsigned short* xn   = (unsigned short*)(w);                  //  4,194,304
  unsigned short* WvT  = (unsigned short*)(w + 4194304);        //  2,621,440
  unsigned short* WoT  = (unsigned short*)(w + 6815744);        //    524,288
  float* alpha         = (float*)(w + 7340032);                 //     81,920
  float* b_v           = (float*)(w + 7421952);                 //     10,240
  float* PA            = (float*)(w + 7432192);                 //      5,120
  float* L             = (float*)(w + 7437312);                 //  2,621,440
  float* Gc            = (float*)(w + 10058752);                //  2,621,440
  unsigned short* vg   = (unsigned short*)(w + 12680192);       // 20,971,520
  unsigned short* ybf  = (unsigned short*)(w + 33651712);       //  4,194,304  (end ~37.8 MB)

  hipLaunchKernelGGL(k_prep_wv,  dim3(128), dim3(256), 0, stream, W_in, b_in, mix, WvT, b_v);
  hipLaunchKernelGGL(k_prep_wout,dim3(128), dim3(256), 0, stream, W_out, WoT);
  hipLaunchKernelGGL(k_ln_gate,  dim3(MM),  dim3(256), 0, stream, hs, gamma, beta, W1, b1, W2, b2, ltau, xn, alpha);
  hipLaunchKernelGGL((k_gemm<128,NV,false>), dim3(NV/128, MM/128), dim3(256), 0, stream,
                     xn, WvT, b_v, nullptr, nullptr, nullptr, vg);
  hipLaunchKernelGGL(k_scan_a,   dim3(BB*NCH), dim3(256), 0, stream, alpha, vg, L, PA);
  hipLaunchKernelGGL(k_scan_b,   dim3(BB*TT), dim3(512), 0, stream, mix, h_prev, PA, L, Gc);
  hipLaunchKernelGGL(k_scan_c,   dim3(BB*NCH), dim3(256), 0, stream, alpha, vg, Gc, ybf);
  hipLaunchKernelGGL((k_gemm<64,DD,true>), dim3(DD/64, MM/128), dim3(256), 0, stream,
                     ybf, WoT, b_out, hs, scale, out, nullptr);
}

// Round 3
// 85.331 us; speedup vs baseline: 1.2937x; 1.1053x over previous
//
#include <hip/hip_runtime.h>
#include <hip/hip_bf16.h>
#include <stdint.h>

#define BB 2
#define SS 2048
#define DD 512
#define PP 13
#define TT 5
#define MH 64
#define MM (BB*SS)      // 4096 rows
#define NV (TT*DD)      // 2560
#define KK 512
#define CHUNK 16
#define NCH (SS/CHUNK)  // 128

typedef __attribute__((ext_vector_type(4))) float f32x4;
typedef __attribute__((ext_vector_type(8))) short s8v;
typedef unsigned int u32;
typedef __attribute__((address_space(3))) u32 lds_u32_t;
typedef __attribute__((address_space(1))) const u32 glb_u32_t;

__device__ __forceinline__ float bf2f(unsigned short u){
  union { unsigned int i; float f; } c; c.i = ((unsigned int)u) << 16; return c.f;
}
__device__ __forceinline__ unsigned short f2bf(float f){
  union { float f; unsigned int i; } c; c.f = f;
  unsigned int x = c.i;
  unsigned int r = (x + 0x7fffu + ((x >> 16) & 1u)) >> 16;
  return (unsigned short)r;
}
// async global->LDS, 16B per lane; LDS dest is wave-uniform base + lane*16
__device__ __forceinline__ void gld16(unsigned short* l, const unsigned short* g){
  __builtin_amdgcn_global_load_lds((glb_u32_t*)g, (lds_u32_t*)l, 16, 0, 0);
}

// ---------------------------------------------------------------- merged prep:
// blocks [0,128): W_vT = mix-contracted W_in (transposed bf16) + b_v
// blocks [128,256): W_outT bf16
// blocks [256,272): W1T bf16
__global__ __launch_bounds__(256) void k_prep(
    const float* __restrict__ W_in, const float* __restrict__ b_in,
    const float* __restrict__ mix,  const float* __restrict__ W_out,
    const float* __restrict__ W1,
    unsigned short* __restrict__ W_vT, float* __restrict__ b_v,
    unsigned short* __restrict__ W_outT, unsigned short* __restrict__ W1T)
{
  int blk = blockIdx.x;
  if (blk < 128){
    int idx = blk * 256 + threadIdx.x;   // 32768 total
    int d  = idx & (DD-1);
    int k0 = idx >> 9;                   // 0..63 (8 k's each)
    float mx[PP][TT];
    #pragma unroll
    for (int p=0;p<PP;++p)
      #pragma unroll
      for (int t=0;t<TT;++t) mx[p][t] = mix[p*TT+t];
    float acc[TT][8];
    #pragma unroll
    for (int t=0;t<TT;++t)
      #pragma unroll
      for (int j=0;j<8;++j) acc[t][j] = 0.f;
    #pragma unroll
    for (int j=0;j<8;++j){
      int k = k0*8 + j;
      const float* wrow = W_in + (size_t)k * (PP*DD) + d;
      #pragma unroll
      for (int p=0;p<PP;++p){
        float w = wrow[p*DD];
        #pragma unroll
        for (int t=0;t<TT;++t) acc[t][j] += mx[p][t]*w;
      }
    }
    #pragma unroll
    for (int t=0;t<TT;++t){
      union { unsigned short us[8]; uint4 u; } pk;
      #pragma unroll
      for (int j=0;j<8;++j) pk.us[j] = f2bf(acc[t][j]);
      *(uint4*)(W_vT + ((size_t)(t*DD+d))*KK + k0*8) = pk.u;
    }
    if (k0 == 0){
      #pragma unroll
      for (int t=0;t<TT;++t){
        float s = 0.f;
        #pragma unroll
        for (int p=0;p<PP;++p) s += mx[p][t]*b_in[p*DD+d];
        b_v[t*DD+d] = s;
      }
    }
  } else if (blk < 256){
    int idx = (blk-128)*256 + threadIdx.x; // 32768
    int n  = idx & (DD-1);
    int k0 = idx >> 9;
    union { unsigned short us[8]; uint4 u; } pk;
    #pragma unroll
    for (int j=0;j<8;++j) pk.us[j] = f2bf(W_out[(size_t)(k0*8+j)*DD + n]);
    *(uint4*)(W_outT + (size_t)n*KK + k0*8) = pk.u;
  } else {
    int idx = (blk-256)*256 + threadIdx.x; // 4096
    int n  = idx >> 6;       // 0..63
    int k0 = idx & 63;       // 8 k's each
    union { unsigned short us[8]; uint4 u; } pk;
    #pragma unroll
    for (int j=0;j<8;++j) pk.us[j] = f2bf(W1[(size_t)(k0*8+j)*MH + n]);
    *(uint4*)(W1T + (size_t)n*KK + k0*8) = pk.u;
  }
}

// ---------------------------------------------------------------- LayerNorm only: 1 wave per row, 4 rows/block
__global__ __launch_bounds__(256) void k_ln(
    const float* __restrict__ hs,
    const float* __restrict__ gamma, const float* __restrict__ beta,
    unsigned short* __restrict__ xn_bf)
{
  int tid = threadIdx.x;
  int lane = tid & 63;
  int row = blockIdx.x*4 + (tid>>6);
  const float* x = hs + (size_t)row*DD + lane*8;
  float4 v0 = *(const float4*)x;
  float4 v1 = *(const float4*)(x+4);
  float s  = v0.x+v0.y+v0.z+v0.w + v1.x+v1.y+v1.z+v1.w;
  float sq = v0.x*v0.x+v0.y*v0.y+v0.z*v0.z+v0.w*v0.w
           + v1.x*v1.x+v1.y*v1.y+v1.z*v1.z+v1.w*v1.w;
  #pragma unroll
  for (int o=32;o>0;o>>=1){ s += __shfl_xor(s,o); sq += __shfl_xor(sq,o); }
  float mu   = s  * (1.f/DD);
  float var  = sq * (1.f/DD) - mu*mu;
  float rstd = rsqrtf(var + 1e-5f);
  float4 g0 = *(const float4*)(gamma + lane*8);
  float4 g1 = *(const float4*)(gamma + lane*8 + 4);
  float4 b0 = *(const float4*)(beta  + lane*8);
  float4 b1 = *(const float4*)(beta  + lane*8 + 4);
  union { unsigned short us[8]; uint4 u; } pk;
  pk.us[0] = f2bf((v0.x-mu)*rstd*g0.x + b0.x);
  pk.us[1] = f2bf((v0.y-mu)*rstd*g0.y + b0.y);
  pk.us[2] = f2bf((v0.z-mu)*rstd*g0.z + b0.z);
  pk.us[3] = f2bf((v0.w-mu)*rstd*g0.w + b0.w);
  pk.us[4] = f2bf((v1.x-mu)*rstd*g1.x + b1.x);
  pk.us[5] = f2bf((v1.y-mu)*rstd*g1.y + b1.y);
  pk.us[6] = f2bf((v1.z-mu)*rstd*g1.z + b1.z);
  pk.us[7] = f2bf((v1.w-mu)*rstd*g1.w + b1.w);
  *(uint4*)(xn_bf + (size_t)row*DD + lane*8) = pk.u;
}

// ---------------------------------------------------------------- gate: z1=tanh(xn@W1), z2=z1@W2+b2, alpha=exp(-sigmoid(z2)/tau)
// 64 rows/block, MFMA over K=512, 2-phase dbuf staging.
__global__ __launch_bounds__(256) void k_gate(
    const unsigned short* __restrict__ xn,
    const unsigned short* __restrict__ W1T,
    const float* __restrict__ b1, const float* __restrict__ W2,
    const float* __restrict__ b2, const float* __restrict__ ltau,
    float* __restrict__ alpha)
{
  __shared__ unsigned short lA[2][64*32];
  __shared__ unsigned short lB[2][64*32];
  int bm = blockIdx.x;
  int tid = threadIdx.x, lane = tid & 63, w = tid >> 6;
  int lr = lane & 15, kq = lane >> 4;
  const uint8_t* gA = (const uint8_t*)(xn  + (size_t)(bm*64 + w*16 + (lane>>2))*KK) + (lane&3)*16;
  const uint8_t* gB = (const uint8_t*)(W1T + (size_t)(        w*16 + (lane>>2))*KK) + (lane&3)*16;
  f32x4 acc[4];
  #pragma unroll
  for (int ni=0;ni<4;++ni) acc[ni] = (f32x4){0.f,0.f,0.f,0.f};

  auto stage = [&](int buf, int kt){
    int off = kt*64;  // bytes
    gld16(&lA[buf][(w*16)*32], (const unsigned short*)(gA + off));
    gld16(&lB[buf][(w*16)*32], (const unsigned short*)(gB + off));
  };
  auto compute = [&](int buf){
    union { uint4 u; s8v v; } af, bfr[4];
    af.u = *(const uint4*)&lA[buf][(w*16+lr)*32 + kq*8];
    #pragma unroll
    for (int ni=0;ni<4;++ni) bfr[ni].u = *(const uint4*)&lB[buf][(ni*16+lr)*32 + kq*8];
    #pragma unroll
    for (int ni=0;ni<4;++ni)
      acc[ni] = __builtin_amdgcn_mfma_f32_16x16x32_bf16(af.v, bfr[ni].v, acc[ni], 0,0,0);
  };

  stage(0, 0);
  __syncthreads();
  #pragma unroll
  for (int kt=1; kt<16; ++kt){
    stage(kt&1, kt);
    compute((kt&1)^1);
    __syncthreads();
  }
  compute(1);

  // epilogue: lane holds rows {w*16+kq*4+r}, cols h=ni*16+lr
  float z1[4][4];
  #pragma unroll
  for (int ni=0;ni<4;++ni){
    float bb = b1[ni*16+lr];
    #pragma unroll
    for (int r=0;r<4;++r) z1[r][ni] = tanhf(acc[ni][r] + bb);
  }
  float et[TT];
  #pragma unroll
  for (int t=0;t<TT;++t) et[t] = expf(-ltau[t]);
  float a[4][TT];
  #pragma unroll
  for (int t=0;t<TT;++t){
    float w2[4];
    #pragma unroll
    for (int ni=0;ni<4;++ni) w2[ni] = W2[(ni*16+lr)*TT + t];
    #pragma unroll
    for (int r=0;r<4;++r){
      float p = z1[r][0]*w2[0] + z1[r][1]*w2[1] + z1[r][2]*w2[2] + z1[r][3]*w2[3];
      #pragma unroll
      for (int o=8;o>0;o>>=1) p += __shfl_xor(p, o);
      float z2 = p + b2[t];
      float gate = 1.f/(1.f + expf(-z2));
      a[r][t] = expf(-gate * et[t]);
    }
  }
  if (lr < TT){
    int t = lr;
    #pragma unroll
    for (int r=0;r<4;++r){
      int row = bm*64 + w*16 + kq*4 + r;
      alpha[(size_t)row*TT + t] = a[r][t];
    }
  }
}

// ---------------------------------------------------------------- bf16 MFMA GEMM, 2-phase dbuf: C = A(M,K)*Bt(N,K)^T (+bias)[+epilogue]
template<int BN, int NDIM, bool OUTEPI>
__global__ __launch_bounds__(256) void k_gemm(
    const unsigned short* __restrict__ A,
    const unsigned short* __restrict__ Bt,
    const float* __restrict__ bias,
    const float* __restrict__ hidden,
    const float* __restrict__ scale_p,
    float* __restrict__ outF,
    unsigned short* __restrict__ outBf)
{
  constexpr int NI  = (BN == 128) ? 4 : 2;
  constexpr int WNT = BN / 2;
  __shared__ unsigned short lA[2][128*32];
  __shared__ unsigned short lB[2][BN*32];
  int bn = blockIdx.x, bm = blockIdx.y;
  int tid  = threadIdx.x;
  int lane = tid & 63;
  int w    = tid >> 6;
  int wm = w >> 1, wn = w & 1;
  f32x4 acc[4][NI];
  #pragma unroll
  for (int i=0;i<4;++i)
    #pragma unroll
    for (int j=0;j<NI;++j) acc[i][j] = (f32x4){0.f,0.f,0.f,0.f};

  const uint8_t* gA = (const uint8_t*)(A + (size_t)(bm*128 + w*32 + (lane>>2))*KK) + (lane&3)*16;
  const uint8_t* gB;
  if constexpr (BN == 128) gB = (const uint8_t*)(Bt + (size_t)(bn*BN + w*32 + (lane>>2))*KK) + (lane&3)*16;
  else                     gB = (const uint8_t*)(Bt + (size_t)(bn*BN + w*16 + (lane>>2))*KK) + (lane&3)*16;
  int lr = lane & 15, kq = lane >> 4;

  auto stage = [&](int buf, int kt){
    int off = kt*64;  // bytes
    gld16(&lA[buf][(w*32)*32],    (const unsigned short*)(gA + off));
    gld16(&lA[buf][(w*32+16)*32], (const unsigned short*)(gA + (size_t)16*KK*2 + off));
    if constexpr (BN == 128){
      gld16(&lB[buf][(w*32)*32],    (const unsigned short*)(gB + off));
      gld16(&lB[buf][(w*32+16)*32], (const unsigned short*)(gB + (size_t)16*KK*2 + off));
    } else {
      gld16(&lB[buf][(w*16)*32],    (const unsigned short*)(gB + off));
    }
  };
  auto compute = [&](int buf){
    union { uint4 u; s8v v; } af[4], bfr[NI];
    #pragma unroll
    for (int mi=0;mi<4;++mi) af[mi].u  = *(const uint4*)&lA[buf][(wm*64+mi*16+lr)*32 + kq*8];
    #pragma unroll
    for (int ni=0;ni<NI;++ni) bfr[ni].u = *(const uint4*)&lB[buf][(wn*WNT+ni*16+lr)*32 + kq*8];
    #pragma unroll
    for (int mi=0;mi<4;++mi)
      #pragma unroll
      for (int ni=0;ni<NI;++ni)
        acc[mi][ni] = __builtin_amdgcn_mfma_f32_16x16x32_bf16(af[mi].v, bfr[ni].v, acc[mi][ni], 0,0,0);
  };

  stage(0, 0);
  __syncthreads();
  #pragma unroll
  for (int kt=1; kt<16; ++kt){
    stage(kt&1, kt);
    compute((kt&1)^1);
    __syncthreads();
  }
  compute(1);

  float sc = 0.f;
  if constexpr (OUTEPI) sc = *scale_p;
  #pragma unroll
  for (int mi=0;mi<4;++mi){
    #pragma unroll
    for (int ni=0;ni<NI;++ni){
      int row = bm*128 + wm*64 + mi*16 + kq*4;   // C/D: col=lane&15, row=(lane>>4)*4+reg
      int col = bn*BN  + wn*WNT + ni*16 + lr;
      float bs = bias[col];
      f32x4 c = acc[mi][ni];
      #pragma unroll
      for (int r=0;r<4;++r){
        float val = c[r] + bs;
        size_t off = (size_t)(row+r)*NDIM + col;
        if constexpr (OUTEPI) outF[off] = hidden[off] + sc*val;
        else                  outBf[off] = f2bf(val);
      }
    }
  }
}

// ---------------------------------------------------------------- scan phase A: per (b,chunk), all t: chunk-local zero-init scan
__global__ __launch_bounds__(256) void k_scan_a(
    const float* __restrict__ alpha,
    const unsigned short* __restrict__ vg,
    float* __restrict__ L, float* __restrict__ PA)
{
  int blk = blockIdx.x;           // b*NCH + c
  int c = blk % NCH, b = blk / NCH;
  int tid = threadIdx.x;          // d0 = 2*tid
  __shared__ float sAl[CHUNK*TT];
  if (tid < CHUNK*TT) sAl[tid] = alpha[(size_t)(b*SS + c*CHUNK)*TT + tid];
  __syncthreads();
  float g[TT][2];
  #pragma unroll
  for (int t=0;t<TT;++t){ g[t][0]=0.f; g[t][1]=0.f; }
  const unsigned short* vp = vg + (size_t)(b*SS + c*CHUNK)*NV + tid*2;
  #pragma unroll
  for (int s2=0;s2<CHUNK;++s2){
    #pragma unroll
    for (int t=0;t<TT;++t){
      float a = sAl[s2*TT+t], om = 1.f - a;
      ushort2 vv = *(const ushort2*)(vp + (size_t)s2*NV + t*DD);
      g[t][0] = a*g[t][0] + om*bf2f(vv.x);
      g[t][1] = a*g[t][1] + om*bf2f(vv.y);
    }
  }
  #pragma unroll
  for (int t=0;t<TT;++t){
    float2 o; o.x = g[t][0]; o.y = g[t][1];
    *(float2*)(L + ((size_t)(b*TT+t)*NCH + c)*DD + tid*2) = o;
  }
  if (tid < TT){
    float pa = 1.f;
    #pragma unroll
    for (int s2=0;s2<CHUNK;++s2) pa *= sAl[s2*TT+tid];
    PA[(size_t)(b*TT+tid)*NCH + c] = pa;
  }
}

// ---------------------------------------------------------------- scan phase B: sequential carry over chunks (one block per (b,t))
__global__ __launch_bounds__(512) void k_scan_b(
    const float* __restrict__ mix,
    const float* __restrict__ h_prev,
    const float* __restrict__ PA,
    const float* __restrict__ L,
    float* __restrict__ Gc)
{
  int blk = blockIdx.x;      // b*TT + t  (10 blocks)
  int t = blk % TT, b = blk / TT;
  int d = threadIdx.x;       // 512
  __shared__ float sP[NCH];
  if (d < NCH) sP[d] = PA[(size_t)(b*TT+t)*NCH + d];
  __syncthreads();
  float carry = 0.f;         // g_init = sum_p mix[p,t]*h_prev[b,p,t,d]
  #pragma unroll
  for (int p=0;p<PP;++p)
    carry += mix[p*TT+t] * h_prev[((size_t)(b*PP+p)*TT + t)*DD + d];
  const float* Lp = L  + (size_t)(b*TT+t)*NCH*DD + d;
  float*       gc = Gc + (size_t)(b*TT+t)*NCH*DD + d;
  float buf[8], nbuf[8];
  #pragma unroll
  for (int j=0;j<8;++j) buf[j] = Lp[(size_t)j*DD];
  for (int c0=0;c0<NCH;c0+=8){
    if (c0+8 < NCH){
      #pragma unroll
      for (int j=0;j<8;++j) nbuf[j] = Lp[(size_t)(c0+8+j)*DD];
    }
    #pragma unroll
    for (int j=0;j<8;++j){
      gc[(size_t)(c0+j)*DD] = carry;
      carry = sP[c0+j]*carry + buf[j];
    }
    #pragma unroll
    for (int j=0;j<8;++j) buf[j] = nbuf[j];
  }
}

// ---------------------------------------------------------------- scan phase C: per (b,chunk), rescan with true carry, y = sum_t g
__global__ __launch_bounds__(256) void k_scan_c(
    const float* __restrict__ alpha,
    const unsigned short* __restrict__ vg,
    const float* __restrict__ Gc,
    unsigned short* __restrict__ ybf)
{
  int blk = blockIdx.x;           // b*NCH + c
  int c = blk % NCH, b = blk / NCH;
  int tid = threadIdx.x;
  __shared__ float sAl[CHUNK*TT];
  if (tid < CHUNK*TT) sAl[tid] = alpha[(size_t)(b*SS + c*CHUNK)*TT + tid];
  __syncthreads();
  float g[TT][2];
  #pragma unroll
  for (int t=0;t<TT;++t){
    float2 cv = *(const float2*)(Gc + ((size_t)(b*TT+t)*NCH + c)*DD + tid*2);
    g[t][0] = cv.x; g[t][1] = cv.y;
  }
  const unsigned short* vp = vg + (size_t)(b*SS + c*CHUNK)*NV + tid*2;
  unsigned short* yp = ybf + (size_t)(b*SS + c*CHUNK)*DD + tid*2;
  #pragma unroll
  for (int s2=0;s2<CHUNK;++s2){
    float y0 = 0.f, y1 = 0.f;
    #pragma unroll
    for (int t=0;t<TT;++t){
      float a = sAl[s2*TT+t], om = 1.f - a;
      ushort2 vv = *(const ushort2*)(vp + (size_t)s2*NV + t*DD);
      g[t][0] = a*g[t][0] + om*bf2f(vv.x);
      g[t][1] = a*g[t][1] + om*bf2f(vv.y);
      y0 += g[t][0]; y1 += g[t][1];
    }
    ushort2 o; o.x = f2bf(y0); o.y = f2bf(y1);
    *(ushort2*)(yp + (size_t)s2*DD) = o;
  }
}

// ----------------------------------------------------------------
extern "C" void kernel_launch(void* const* d_in, const int* in_sizes, int n_in,
                              void* d_out, int out_size, void* d_ws, size_t ws_size,
                              hipStream_t stream)
{
  (void)in_sizes; (void)n_in; (void)out_size; (void)ws_size;
  const float* hs     = (const float*)d_in[0];
  const float* gamma  = (const float*)d_in[1];
  const float* beta   = (const float*)d_in[2];
  const float* W_in   = (const float*)d_in[3];
  const float* b_in   = (const float*)d_in[4];
  const float* W1     = (const float*)d_in[5];
  const float* b1     = (const float*)d_in[6];
  const float* W2     = (const float*)d_in[7];
  const float* b2     = (const float*)d_in[8];
  const float* ltau   = (const float*)d_in[9];
  const float* mix    = (const float*)d_in[10];
  const float* W_out  = (const float*)d_in[11];
  const float* b_out  = (const float*)d_in[12];
  const float* scale  = (const float*)d_in[13];
  const float* h_prev = (const float*)d_in[14];
  float* out = (float*)d_out;

  uint8_t* w = (uint8_t*)d_ws;
  unsigned short* xn   = (unsigned short*)(w);                  //  4,194,304
  unsigned short* WvT  = (unsigned short*)(w + 4194304);        //  2,621,440
  unsigned short* WoT  = (unsigned short*)(w + 6815744);        //    524,288
  float* alpha         = (float*)(w + 7340032);                 //     81,920
  float* b_v           = (float*)(w + 7421952);                 //     10,240
  float* PA            = (float*)(w + 7432192);                 //      5,120
  float* L             = (float*)(w + 7437312);                 //  2,621,440
  float* Gc            = (float*)(w + 10058752);                //  2,621,440
  unsigned short* vg   = (unsigned short*)(w + 12680192);       // 20,971,520
  unsigned short* ybf  = (unsigned short*)(w + 33651712);       //  4,194,304
  unsigned short* W1T  = ybf;   // aliased: W1T dead before scan_c writes ybf

  hipLaunchKernelGGL(k_prep, dim3(272), dim3(256), 0, stream,
                     W_in, b_in, mix, W_out, W1, WvT, b_v, WoT, W1T);
  hipLaunchKernelGGL(k_ln,   dim3(MM/4), dim3(256), 0, stream, hs, gamma, beta, xn);
  hipLaunchKernelGGL(k_gate, dim3(MM/64), dim3(256), 0, stream, xn, W1T, b1, W2, b2, ltau, alpha);
  hipLaunchKernelGGL((k_gemm<128,NV,false>), dim3(NV/128, MM/128), dim3(256), 0, stream,
                     xn, WvT, b_v, nullptr, nullptr, nullptr, vg);
  hipLaunchKernelGGL(k_scan_a, dim3(BB*NCH), dim3(256), 0, stream, alpha, vg, L, PA);
  hipLaunchKernelGGL(k_scan_b, dim3(BB*TT), dim3(512), 0, stream, mix, h_prev, PA, L, Gc);
  hipLaunchKernelGGL(k_scan_c, dim3(BB*NCH), dim3(256), 0, stream, alpha, vg, Gc, ybf);
  hipLaunchKernelGGL((k_gemm<64,DD,true>), dim3(DD/64, MM/128), dim3(256), 0, stream,
                     ybf, WoT, b_out, hs, scale, out, nullptr);
}